// Round 12
// baseline (160.937 us; speedup 1.0000x reference)
//
#include <hip/hip_runtime.h>
#include <hip/hip_bf16.h>

#define N_NODES 50000
#define N_EDGES 800000
#define N_GRAPHS 64
#define IN_C 128
#define HID 96
#define SLICES 8
#define NBUCK 196      // node buckets of 256 nodes
#define NCHK 200       // edge chunks
#define EPC 4000       // edges per chunk (NCHK*EPC == N_EDGES)

typedef short s16x8 __attribute__((ext_vector_type(8)));
typedef float f32x4 __attribute__((ext_vector_type(4)));

__device__ inline unsigned short f2bf(float f) {
    union { __hip_bfloat16 b; unsigned short u; } cv;
    cv.b = __float2bfloat16(f);
    return cv.u;
}
__device__ inline float bf2f(unsigned short u) { return __uint_as_float((unsigned int)u << 16); }
__device__ inline float bf_lo(unsigned int u) { return __uint_as_float(u << 16); }
__device__ inline float bf_hi(unsigned int u) { return __uint_as_float(u & 0xffff0000u); }
__device__ inline unsigned int pack2(float lo, float hi) {
    return (unsigned)f2bf(lo) | ((unsigned)f2bf(hi) << 16);
}
__device__ inline void acc8(float* a, uint4 r) {
    a[0] += bf_lo(r.x); a[1] += bf_hi(r.x);
    a[2] += bf_lo(r.y); a[3] += bf_hi(r.y);
    a[4] += bf_lo(r.z); a[5] += bf_hi(r.z);
    a[6] += bf_lo(r.w); a[7] += bf_hi(r.w);
}

// ---------- preprocessing ----------

// P1: per-chunk coarse histogram (dst>>8) + graph bounds (batch sorted)
__global__ __launch_bounds__(256)
void p1_hist(const int* __restrict__ dst, int* __restrict__ chunkHist,
             const int* __restrict__ batch, int* __restrict__ gstart, int* __restrict__ gend) {
    __shared__ int h[NBUCK];
    int c = blockIdx.x, t = threadIdx.x;
    for (int i = t; i < NBUCK; i += 256) h[i] = 0;
    __syncthreads();
    int base = c * EPC;
    for (int i = t; i < EPC; i += 256)
        atomicAdd(&h[dst[base + i] >> 8], 1);
    __syncthreads();
    for (int i = t; i < NBUCK; i += 256) chunkHist[c * NBUCK + i] = h[i];

    int gi = c * 256 + t;
    if (gi < N_NODES) {
        int g = batch[gi];
        if (gi == 0) {
            gstart[g] = 0;
        } else {
            int gp = batch[gi - 1];
            if (gp != g) { gstart[g] = gi; gend[gp] = gi - 1; }
        }
        if (gi == N_NODES - 1) gend[g] = N_NODES - 1;
    }
}

// P2: per-bucket scan over chunks; last block also scans bucket totals -> bucketBase
__global__ __launch_bounds__(256)
void p2_scan(const int* __restrict__ chunkHist, int* __restrict__ offTabRel,
             int* __restrict__ bucketTot, int* __restrict__ bucketBase,
             int* __restrict__ rowstart, int* __restrict__ p2done) {
    __shared__ int sh[256];
    __shared__ int lastF;
    int b = blockIdx.x, t = threadIdx.x;
    int v = (t < NCHK) ? chunkHist[t * NBUCK + b] : 0;
    sh[t] = v;
    __syncthreads();
    for (int off = 1; off < 256; off <<= 1) {
        int x = (t >= off) ? sh[t - off] : 0;
        __syncthreads();
        sh[t] += x;
        __syncthreads();
    }
    if (t < NCHK) offTabRel[t * NBUCK + b] = sh[t] - v;
    if (t == 255) {
        atomicExch(&bucketTot[b], sh[255]);
        __threadfence();
    }
    __syncthreads();
    if (t == 0) lastF = (atomicAdd(p2done, 1) == NBUCK - 1) ? 1 : 0;
    __syncthreads();
    if (lastF) {
        int bt = (t < NBUCK) ? atomicAdd(&bucketTot[t], 0) : 0;
        __syncthreads();
        sh[t] = bt;
        __syncthreads();
        for (int off = 1; off < 256; off <<= 1) {
            int x = (t >= off) ? sh[t - off] : 0;
            __syncthreads();
            sh[t] += x;
            __syncthreads();
        }
        if (t < NBUCK) bucketBase[t] = sh[t] - bt;
        if (t == 0) { bucketBase[NBUCK] = N_EDGES; rowstart[N_NODES] = N_EDGES; }
    }
}

// P3: place packed (fine<<16 | src) into per-(chunk,bucket) windows
__global__ __launch_bounds__(256)
void p3_place(const int* __restrict__ src, const int* __restrict__ dst,
              const int* __restrict__ offTabRel, const int* __restrict__ bucketBase,
              unsigned int* __restrict__ epacked) {
    __shared__ int cur[NBUCK];
    int c = blockIdx.x, t = threadIdx.x;
    for (int i = t; i < NBUCK; i += 256)
        cur[i] = bucketBase[i] + offTabRel[c * NBUCK + i];
    __syncthreads();
    int base = c * EPC;
    for (int i = t; i < EPC; i += 256) {
        int d = dst[base + i];
        int s = src[base + i];
        int pos = atomicAdd(&cur[d >> 8], 1);
        epacked[pos] = ((unsigned)(d & 255) << 16) | (unsigned)s;
    }
}

// P4: per-bucket fine counting sort -> rowstart, dinv, u16 src list
__global__ __launch_bounds__(256)
void p4_fine(const unsigned int* __restrict__ epacked, const int* __restrict__ bucketBase,
             int* __restrict__ rowstart, float* __restrict__ dinv,
             unsigned short* __restrict__ e_src16) {
    __shared__ int h[256];
    __shared__ int rs[256];
    __shared__ unsigned short sorted[8192];
    int b = blockIdx.x, t = threadIdx.x;
    int s0 = bucketBase[b], len = bucketBase[b + 1] - s0;
    h[t] = 0;
    __syncthreads();
    for (int i = t; i < len; i += 256)
        atomicAdd(&h[(epacked[s0 + i] >> 16) & 255], 1);
    __syncthreads();
    int deg = h[t];
    rs[t] = deg;
    __syncthreads();
    for (int off = 1; off < 256; off <<= 1) {
        int x = (t >= off) ? rs[t - off] : 0;
        __syncthreads();
        rs[t] += x;
        __syncthreads();
    }
    int myrow = rs[t] - deg;
    int node = b * 256 + t;
    if (node < N_NODES) {
        rowstart[node] = s0 + myrow;
        dinv[node] = rsqrtf((float)deg + 1.0f);
    }
    __syncthreads();
    h[t] = myrow;
    __syncthreads();
    for (int i = t; i < len; i += 256) {
        unsigned int p = epacked[s0 + i];
        int pos = atomicAdd(&h[(p >> 16) & 255], 1);
        sorted[pos] = (unsigned short)(p & 0xffffu);
    }
    __syncthreads();
    for (int i = t; i < len; i += 256) e_src16[s0 + i] = sorted[i];
}

// ---------- MFMA GEMM ----------
template <int K, bool PRENORM>
__global__ __launch_bounds__(256)
void gemm_mfma(const void* __restrict__ Xv, const float* __restrict__ W,
               const float* __restrict__ dinv, const int* __restrict__ batch,
               const float* __restrict__ gA, const float* __restrict__ gB,
               unsigned short* __restrict__ Hp) {
    constexpr int KP = K + 8;
    constexpr int KS = K / 32;
    __shared__ unsigned short Wt[96 * KP];
    int tid = threadIdx.x;
    for (int idx = tid; idx < K * 96; idx += 256) {
        int k = idx / 96, c = idx - k * 96;
        Wt[c * KP + k] = f2bf(W[idx]);
    }
    __syncthreads();

    const int lane = tid & 63;
    const int quad = lane >> 4;
    const int l16 = lane & 15;

    s16x8 Bf[6][KS];
#pragma unroll
    for (int t = 0; t < 6; ++t)
#pragma unroll
        for (int s = 0; s < KS; ++s)
            Bf[t][s] = *(const s16x8*)&Wt[(t * 16 + l16) * KP + s * 32 + quad * 8];

    int gw = blockIdx.x * 4 + (tid >> 6);
    int nw = gridDim.x * 4;
    for (int tile = gw; tile < N_NODES / 16; tile += nw) {
        int n0 = tile * 16;
        int row = n0 + l16;
        s16x8 Af[KS];
        if (!PRENORM) {
            const float* Xr = (const float*)Xv + (size_t)row * K;
#pragma unroll
            for (int s = 0; s < KS; ++s) {
                int k0 = s * 32 + quad * 8;
                float4 u = *(const float4*)(Xr + k0);
                float4 v = *(const float4*)(Xr + k0 + 4);
                s16x8 a;
                a[0] = (short)f2bf(u.x); a[1] = (short)f2bf(u.y);
                a[2] = (short)f2bf(u.z); a[3] = (short)f2bf(u.w);
                a[4] = (short)f2bf(v.x); a[5] = (short)f2bf(v.y);
                a[6] = (short)f2bf(v.z); a[7] = (short)f2bf(v.w);
                Af[s] = a;
            }
        } else {
            const unsigned short* Xr = (const unsigned short*)Xv + (size_t)row * HID;
            int g = batch[row];
            const float* ga = gA + g * HID;
            const float* gb = gB + g * HID;
#pragma unroll
            for (int s = 0; s < KS; ++s) {
                int k0 = s * 32 + quad * 8;
                uint4 raw = *(const uint4*)(Xr + k0);
                float4 a0 = *(const float4*)(ga + k0);
                float4 a1 = *(const float4*)(ga + k0 + 4);
                float4 b0 = *(const float4*)(gb + k0);
                float4 b1 = *(const float4*)(gb + k0 + 4);
                s16x8 a;
                a[0] = (short)f2bf(fmaxf(fmaf(bf_lo(raw.x), a0.x, b0.x), 0.f));
                a[1] = (short)f2bf(fmaxf(fmaf(bf_hi(raw.x), a0.y, b0.y), 0.f));
                a[2] = (short)f2bf(fmaxf(fmaf(bf_lo(raw.y), a0.z, b0.z), 0.f));
                a[3] = (short)f2bf(fmaxf(fmaf(bf_hi(raw.y), a0.w, b0.w), 0.f));
                a[4] = (short)f2bf(fmaxf(fmaf(bf_lo(raw.z), a1.x, b1.x), 0.f));
                a[5] = (short)f2bf(fmaxf(fmaf(bf_hi(raw.z), a1.y, b1.y), 0.f));
                a[6] = (short)f2bf(fmaxf(fmaf(bf_lo(raw.w), a1.z, b1.z), 0.f));
                a[7] = (short)f2bf(fmaxf(fmaf(bf_hi(raw.w), a1.w, b1.w), 0.f));
                Af[s] = a;
            }
        }
        f32x4 acc[6];
#pragma unroll
        for (int t = 0; t < 6; ++t) { acc[t][0] = 0.f; acc[t][1] = 0.f; acc[t][2] = 0.f; acc[t][3] = 0.f; }
#pragma unroll
        for (int s = 0; s < KS; ++s)
#pragma unroll
            for (int t = 0; t < 6; ++t)
                acc[t] = __builtin_amdgcn_mfma_f32_16x16x32_bf16(Af[s], Bf[t][s], acc[t], 0, 0, 0);

        float4 dv = *(const float4*)(dinv + n0 + quad * 4);
#pragma unroll
        for (int t = 0; t < 6; ++t) {
            size_t base = (size_t)(n0 + quad * 4) * HID + t * 16 + l16;
            Hp[base]            = f2bf(acc[t][0] * dv.x);
            Hp[base + HID]      = f2bf(acc[t][1] * dv.y);
            Hp[base + 2 * HID]  = f2bf(acc[t][2] * dv.z);
            Hp[base + 3 * HID]  = f2bf(acc[t][3] * dv.w);
        }
    }
}

// ---------- aggregation: block (12,32), 2 nodes/thread, unroll 4 ----------
__global__ __launch_bounds__(384)
void agg_kernel(const int* __restrict__ rowstart, const unsigned short* __restrict__ e_src,
                const float* __restrict__ dinv, const unsigned short* __restrict__ H,
                const float* __restrict__ bias, unsigned short* __restrict__ OUT) {
    int x = threadIdx.x;   // 0..11, 8 channels each
    const uint4* H8 = (const uint4*)H;
    float4 b0 = *(const float4*)(bias + x * 8);
    float4 b1 = *(const float4*)(bias + x * 8 + 4);

#pragma unroll
    for (int rep = 0; rep < 2; ++rep) {
        int node = blockIdx.x * 64 + rep * 32 + threadIdx.y;
        if (node >= N_NODES) continue;
        size_t ridx = (size_t)node * 12 + x;
        float a[8] = {0, 0, 0, 0, 0, 0, 0, 0};
        acc8(a, H8[ridx]);   // self (H' pre-scaled by dinv)
        int s0 = rowstart[node], s1 = rowstart[node + 1];
        int i = s0;
        for (; i + 4 <= s1; i += 4) {
            int sA = e_src[i], sB = e_src[i + 1], sC = e_src[i + 2], sD = e_src[i + 3];
            uint4 rA = H8[(size_t)sA * 12 + x];
            uint4 rB = H8[(size_t)sB * 12 + x];
            uint4 rC = H8[(size_t)sC * 12 + x];
            uint4 rD = H8[(size_t)sD * 12 + x];
            acc8(a, rA); acc8(a, rB); acc8(a, rC); acc8(a, rD);
        }
        for (; i < s1; ++i)
            acc8(a, H8[(size_t)e_src[i] * 12 + x]);

        float di = dinv[node];
        uint4 ov;
        ov.x = pack2(fmaf(a[0], di, b0.x), fmaf(a[1], di, b0.y));
        ov.y = pack2(fmaf(a[2], di, b0.z), fmaf(a[3], di, b0.w));
        ov.z = pack2(fmaf(a[4], di, b1.x), fmaf(a[5], di, b1.y));
        ov.w = pack2(fmaf(a[6], di, b1.z), fmaf(a[7], di, b1.w));
        ((uint4*)OUT)[ridx] = ov;
    }
}

// ---------- GraphNorm: partial sums + last-block finalize ----------
__global__ __launch_bounds__(768)
void gn_partial(const unsigned short* __restrict__ Xb, const int* __restrict__ gstart,
                const int* __restrict__ gend, float* __restrict__ gSum, float* __restrict__ gSq,
                int* __restrict__ done, const float* __restrict__ w, const float* __restrict__ b,
                const float* __restrict__ a, float* __restrict__ gA, float* __restrict__ gB) {
    __shared__ float4 sSum[32][24];
    __shared__ float4 sSq[32][24];
    __shared__ int lastFlag;
    int g = blockIdx.x, sl = blockIdx.y;
    int x = threadIdx.x, ty = threadIdx.y;
    int s = gstart[g], e = gend[g];
    float sx = 0, sy = 0, sz = 0, sw = 0, qx = 0, qy = 0, qz = 0, qw = 0;
    if (s <= e) {
        int cnt = e - s + 1;
        int per = (cnt + SLICES - 1) / SLICES;
        int n0 = s + sl * per;
        int n1 = min(n0 + per - 1, e);
        const ushort4* X4 = (const ushort4*)Xb;
        for (int n = n0 + ty; n <= n1; n += 32) {
            ushort4 h = X4[(size_t)n * 24 + x];
            float vx = bf2f(h.x), vy = bf2f(h.y), vz = bf2f(h.z), vw = bf2f(h.w);
            sx += vx; qx = fmaf(vx, vx, qx);
            sy += vy; qy = fmaf(vy, vy, qy);
            sz += vz; qz = fmaf(vz, vz, qz);
            sw += vw; qw = fmaf(vw, vw, qw);
        }
    }
    sSum[ty][x] = make_float4(sx, sy, sz, sw);
    sSq[ty][x] = make_float4(qx, qy, qz, qw);
    __syncthreads();
    for (int off = 16; off > 0; off >>= 1) {
        if (ty < off) {
            float4 A = sSum[ty + off][x], B = sSum[ty][x];
            sSum[ty][x] = make_float4(A.x + B.x, A.y + B.y, A.z + B.z, A.w + B.w);
            float4 C = sSq[ty + off][x], D = sSq[ty][x];
            sSq[ty][x] = make_float4(C.x + D.x, C.y + D.y, C.z + D.z, C.w + D.w);
        }
        __syncthreads();
    }
    if (ty == 0) {
        float4 S = sSum[0][x], Q = sSq[0][x];
        atomicAdd(&gSum[g * HID + x * 4 + 0], S.x);
        atomicAdd(&gSum[g * HID + x * 4 + 1], S.y);
        atomicAdd(&gSum[g * HID + x * 4 + 2], S.z);
        atomicAdd(&gSum[g * HID + x * 4 + 3], S.w);
        atomicAdd(&gSq[g * HID + x * 4 + 0], Q.x);
        atomicAdd(&gSq[g * HID + x * 4 + 1], Q.y);
        atomicAdd(&gSq[g * HID + x * 4 + 2], Q.z);
        atomicAdd(&gSq[g * HID + x * 4 + 3], Q.w);
        __threadfence();
    }
    __syncthreads();
    if (ty == 0 && x == 0) {
        int old = atomicAdd(&done[g], 1);
        lastFlag = (old == SLICES - 1) ? 1 : 0;
    }
    __syncthreads();
    if (lastFlag) {
        int t = ty * 24 + x;
        if (t < HID) {
            float S = atomicAdd(&gSum[g * HID + t], 0.0f);   // coherent read
            float Q = atomicAdd(&gSq[g * HID + t], 0.0f);
            float A = 0.f, B = 0.f;
            if (s <= e) {
                float cnt = (float)(e - s + 1);
                float mean = S / cnt;
                float alpha = a[t];
                float var = Q / cnt - (2.f * alpha - alpha * alpha) * mean * mean;
                var = fmaxf(var, 0.f);
                float rsv = rsqrtf(var + 1e-5f);
                A = w[t] * rsv;
                B = b[t] - alpha * mean * A;
            }
            gA[g * HID + t] = A;
            gB[g * HID + t] = B;
        }
    }
}

// final apply: d_out(f32) = relu(bf16(X)*A[g]+B[g]); block (12,32)
__global__ __launch_bounds__(384)
void gn_apply(const unsigned short* __restrict__ Xb, const int* __restrict__ batch,
              const float* __restrict__ gA, const float* __restrict__ gB,
              float* __restrict__ Y) {
    int n = blockIdx.x * 32 + threadIdx.y;
    if (n >= N_NODES) return;
    int x = threadIdx.x;
    int g = batch[n];
    uint4 h = ((const uint4*)Xb)[(size_t)n * 12 + x];
    const float* ga = gA + g * HID + x * 8;
    const float* gb = gB + g * HID + x * 8;
    float4 a0 = *(const float4*)ga, a1 = *(const float4*)(ga + 4);
    float4 b0 = *(const float4*)gb, b1 = *(const float4*)(gb + 4);
    float4 o0, o1;
    o0.x = fmaxf(fmaf(bf_lo(h.x), a0.x, b0.x), 0.f);
    o0.y = fmaxf(fmaf(bf_hi(h.x), a0.y, b0.y), 0.f);
    o0.z = fmaxf(fmaf(bf_lo(h.y), a0.z, b0.z), 0.f);
    o0.w = fmaxf(fmaf(bf_hi(h.y), a0.w, b0.w), 0.f);
    o1.x = fmaxf(fmaf(bf_lo(h.z), a1.x, b1.x), 0.f);
    o1.y = fmaxf(fmaf(bf_hi(h.z), a1.y, b1.y), 0.f);
    o1.z = fmaxf(fmaf(bf_lo(h.w), a1.z, b1.z), 0.f);
    o1.w = fmaxf(fmaf(bf_hi(h.w), a1.w, b1.w), 0.f);
    float* yr = Y + (size_t)n * HID + x * 8;
    *(float4*)yr = o0;
    *(float4*)(yr + 4) = o1;
}

extern "C" void kernel_launch(void* const* d_in, const int* in_sizes, int n_in,
                              void* d_out, int out_size, void* d_ws, size_t ws_size,
                              hipStream_t stream) {
    const float* x     = (const float*)d_in[0];
    const int*   edge  = (const int*)d_in[1];
    const int*   batch = (const int*)d_in[2];
    const float* W1    = (const float*)d_in[3];
    const float* b1    = (const float*)d_in[4];
    const float* gn1_w = (const float*)d_in[5];
    const float* gn1_b = (const float*)d_in[6];
    const float* gn1_a = (const float*)d_in[7];
    const float* W2    = (const float*)d_in[8];
    const float* b2    = (const float*)d_in[9];
    const float* gn2_w = (const float*)d_in[10];
    const float* gn2_b = (const float*)d_in[11];
    const float* gn2_a = (const float*)d_in[12];
    float* out = (float*)d_out;

    const int* srcv = edge;
    const int* dstv = edge + N_EDGES;

    float* ws   = (float*)d_ws;
    float* dinv = ws;                          // 50048 f
    float* gA   = dinv + 50048;                // 6144 f
    float* gB   = gA + 6144;                   // 6144 f
    // --- single zero-memset block: stats + ALL counters (distinct arrays!) ---
    float* zb    = gB + 6144;
    float* gSum1 = zb;                         // 6144
    float* gSq1  = gSum1 + 6144;               // 6144
    float* gSum2 = gSq1 + 6144;                // 6144
    float* gSq2  = gSum2 + 6144;               // 6144
    int* done1   = (int*)(gSq2 + 6144);        // 64 (per-graph, layer 1)
    int* done2   = done1 + 64;                 // 64 (per-graph, layer 2)
    int* p2done  = done2 + 64;                 // 64 (scalar + pad)
    const size_t ZB_BYTES = (4 * 6144 + 3 * 64) * sizeof(float);
    // --- rest (written deterministically by kernels, no init needed) ---
    int* gstart  = p2done + 64;                // 64
    int* gend    = gstart + 64;                // 64
    int* rowstart   = gend + 64;               // 50008
    int* chunkHist  = rowstart + 50008;        // 39200
    int* offTabRel  = chunkHist + NCHK * NBUCK;// 39200
    int* bucketTot  = offTabRel + NCHK * NBUCK;// 200 (pad)
    int* bucketBase = bucketTot + 200;         // 200 (pad, 197 used)
    unsigned int* epacked = (unsigned int*)(bucketBase + 200);      // 800000 u32
    unsigned short* e_src16 = (unsigned short*)(epacked + N_EDGES); // 800000 u16
    unsigned short* Hbf = e_src16 + N_EDGES;                        // 4.8M bf16
    unsigned short* Obf = Hbf + (size_t)N_NODES * HID;              // 4.8M bf16

    // ---- preprocessing ----
    hipMemsetAsync(zb, 0, ZB_BYTES, stream);
    p1_hist<<<NCHK, 256, 0, stream>>>(dstv, chunkHist, batch, gstart, gend);
    p2_scan<<<NBUCK, 256, 0, stream>>>(chunkHist, offTabRel, bucketTot, bucketBase,
                                       rowstart, p2done);
    p3_place<<<NCHK, 256, 0, stream>>>(srcv, dstv, offTabRel, bucketBase, epacked);
    p4_fine<<<NBUCK, 256, 0, stream>>>(epacked, bucketBase, rowstart, dinv, e_src16);

    const dim3 blk12x32(12, 32);
    const dim3 blk24x32(24, 32);
    const int aggGrid = (N_NODES + 63) / 64;      // 782 (2 nodes/thread)
    const int nodeGrid32 = (N_NODES + 31) / 32;   // 1563

    // ---------- layer 1 ----------
    gemm_mfma<IN_C, false><<<391, 256, 0, stream>>>(x, W1, dinv, nullptr, nullptr, nullptr, Hbf);
    agg_kernel<<<aggGrid, blk12x32, 0, stream>>>(rowstart, e_src16, dinv, Hbf, b1, Obf);
    gn_partial<<<dim3(N_GRAPHS, SLICES), blk24x32, 0, stream>>>(Obf, gstart, gend, gSum1, gSq1,
                                                                done1, gn1_w, gn1_b, gn1_a, gA, gB);

    // ---------- layer 2 (gn_apply+relu of layer 1 fused into A-frag load) ----------
    gemm_mfma<HID, true><<<391, 256, 0, stream>>>(Obf, W2, dinv, batch, gA, gB, Hbf);
    agg_kernel<<<aggGrid, blk12x32, 0, stream>>>(rowstart, e_src16, dinv, Hbf, b2, Obf);
    gn_partial<<<dim3(N_GRAPHS, SLICES), blk24x32, 0, stream>>>(Obf, gstart, gend, gSum2, gSq2,
                                                                done2, gn2_w, gn2_b, gn2_a, gA, gB);
    gn_apply<<<nodeGrid32, blk12x32, 0, stream>>>(Obf, batch, gA, gB, out);
}

// Round 13
// 158.510 us; speedup vs baseline: 1.0153x; 1.0153x over previous
//
#include <hip/hip_runtime.h>
#include <hip/hip_bf16.h>

#define N_NODES 50000
#define N_EDGES 800000
#define N_GRAPHS 64
#define IN_C 128
#define HID 96
#define SLICES 8
#define NBUCK 196      // node buckets of 256 nodes
#define NCHK 200       // edge chunks
#define EPC 4000       // edges per chunk (NCHK*EPC == N_EDGES)

typedef short s16x8 __attribute__((ext_vector_type(8)));
typedef float f32x4 __attribute__((ext_vector_type(4)));

__device__ inline unsigned short f2bf(float f) {
    union { __hip_bfloat16 b; unsigned short u; } cv;
    cv.b = __float2bfloat16(f);
    return cv.u;
}
__device__ inline float bf2f(unsigned short u) { return __uint_as_float((unsigned int)u << 16); }
__device__ inline float bf_lo(unsigned int u) { return __uint_as_float(u << 16); }
__device__ inline float bf_hi(unsigned int u) { return __uint_as_float(u & 0xffff0000u); }
__device__ inline unsigned int pack2(float lo, float hi) {
    return (unsigned)f2bf(lo) | ((unsigned)f2bf(hi) << 16);
}
__device__ inline void acc8(float* a, uint4 r) {
    a[0] += bf_lo(r.x); a[1] += bf_hi(r.x);
    a[2] += bf_lo(r.y); a[3] += bf_hi(r.y);
    a[4] += bf_lo(r.z); a[5] += bf_hi(r.z);
    a[6] += bf_lo(r.w); a[7] += bf_hi(r.w);
}

// ---------- preprocessing ----------

// P1: per-chunk coarse histogram (dst>>8) + graph bounds (batch sorted)
__global__ __launch_bounds__(256)
void p1_hist(const int* __restrict__ dst, int* __restrict__ chunkHist,
             const int* __restrict__ batch, int* __restrict__ gstart, int* __restrict__ gend) {
    __shared__ int h[NBUCK];
    int c = blockIdx.x, t = threadIdx.x;
    for (int i = t; i < NBUCK; i += 256) h[i] = 0;
    __syncthreads();
    int base = c * EPC;
    for (int i = t; i < EPC; i += 256)
        atomicAdd(&h[dst[base + i] >> 8], 1);
    __syncthreads();
    for (int i = t; i < NBUCK; i += 256) chunkHist[c * NBUCK + i] = h[i];

    int gi = c * 256 + t;
    if (gi < N_NODES) {
        int g = batch[gi];
        if (gi == 0) {
            gstart[g] = 0;
        } else {
            int gp = batch[gi - 1];
            if (gp != g) { gstart[g] = gi; gend[gp] = gi - 1; }
        }
        if (gi == N_NODES - 1) gend[g] = N_NODES - 1;
    }
}

// P2: per-bucket scan over chunks; last block also scans bucket totals -> bucketBase
__global__ __launch_bounds__(256)
void p2_scan(const int* __restrict__ chunkHist, int* __restrict__ offTabRel,
             int* __restrict__ bucketTot, int* __restrict__ bucketBase,
             int* __restrict__ rowstart, int* __restrict__ p2done) {
    __shared__ int sh[256];
    __shared__ int lastF;
    int b = blockIdx.x, t = threadIdx.x;
    int v = (t < NCHK) ? chunkHist[t * NBUCK + b] : 0;
    sh[t] = v;
    __syncthreads();
    for (int off = 1; off < 256; off <<= 1) {
        int x = (t >= off) ? sh[t - off] : 0;
        __syncthreads();
        sh[t] += x;
        __syncthreads();
    }
    if (t < NCHK) offTabRel[t * NBUCK + b] = sh[t] - v;
    if (t == 255) {
        atomicExch(&bucketTot[b], sh[255]);
        __threadfence();
    }
    __syncthreads();
    if (t == 0) lastF = (atomicAdd(p2done, 1) == NBUCK - 1) ? 1 : 0;
    __syncthreads();
    if (lastF) {
        int bt = (t < NBUCK) ? atomicAdd(&bucketTot[t], 0) : 0;
        __syncthreads();
        sh[t] = bt;
        __syncthreads();
        for (int off = 1; off < 256; off <<= 1) {
            int x = (t >= off) ? sh[t - off] : 0;
            __syncthreads();
            sh[t] += x;
            __syncthreads();
        }
        if (t < NBUCK) bucketBase[t] = sh[t] - bt;
        if (t == 0) { bucketBase[NBUCK] = N_EDGES; rowstart[N_NODES] = N_EDGES; }
    }
}

// P3: place packed (fine<<16 | src) into per-(chunk,bucket) windows
__global__ __launch_bounds__(256)
void p3_place(const int* __restrict__ src, const int* __restrict__ dst,
              const int* __restrict__ offTabRel, const int* __restrict__ bucketBase,
              unsigned int* __restrict__ epacked) {
    __shared__ int cur[NBUCK];
    int c = blockIdx.x, t = threadIdx.x;
    for (int i = t; i < NBUCK; i += 256)
        cur[i] = bucketBase[i] + offTabRel[c * NBUCK + i];
    __syncthreads();
    int base = c * EPC;
    for (int i = t; i < EPC; i += 256) {
        int d = dst[base + i];
        int s = src[base + i];
        int pos = atomicAdd(&cur[d >> 8], 1);
        epacked[pos] = ((unsigned)(d & 255) << 16) | (unsigned)s;
    }
}

// P4: per-bucket fine counting sort -> rowstart, dinv, u16 src list
__global__ __launch_bounds__(256)
void p4_fine(const unsigned int* __restrict__ epacked, const int* __restrict__ bucketBase,
             int* __restrict__ rowstart, float* __restrict__ dinv,
             unsigned short* __restrict__ e_src16) {
    __shared__ int h[256];
    __shared__ int rs[256];
    __shared__ unsigned short sorted[8192];
    int b = blockIdx.x, t = threadIdx.x;
    int s0 = bucketBase[b], len = bucketBase[b + 1] - s0;
    h[t] = 0;
    __syncthreads();
    for (int i = t; i < len; i += 256)
        atomicAdd(&h[(epacked[s0 + i] >> 16) & 255], 1);
    __syncthreads();
    int deg = h[t];
    rs[t] = deg;
    __syncthreads();
    for (int off = 1; off < 256; off <<= 1) {
        int x = (t >= off) ? rs[t - off] : 0;
        __syncthreads();
        rs[t] += x;
        __syncthreads();
    }
    int myrow = rs[t] - deg;
    int node = b * 256 + t;
    if (node < N_NODES) {
        rowstart[node] = s0 + myrow;
        dinv[node] = rsqrtf((float)deg + 1.0f);
    }
    __syncthreads();
    h[t] = myrow;
    __syncthreads();
    for (int i = t; i < len; i += 256) {
        unsigned int p = epacked[s0 + i];
        int pos = atomicAdd(&h[(p >> 16) & 255], 1);
        sorted[pos] = (unsigned short)(p & 0xffffu);
    }
    __syncthreads();
    for (int i = t; i < len; i += 256) e_src16[s0 + i] = sorted[i];
}

// ---------- MFMA GEMM ----------
template <int K, bool PRENORM>
__global__ __launch_bounds__(256)
void gemm_mfma(const void* __restrict__ Xv, const float* __restrict__ W,
               const float* __restrict__ dinv, const int* __restrict__ batch,
               const float* __restrict__ gA, const float* __restrict__ gB,
               unsigned short* __restrict__ Hp) {
    constexpr int KP = K + 8;
    constexpr int KS = K / 32;
    __shared__ unsigned short Wt[96 * KP];
    int tid = threadIdx.x;
    for (int idx = tid; idx < K * 96; idx += 256) {
        int k = idx / 96, c = idx - k * 96;
        Wt[c * KP + k] = f2bf(W[idx]);
    }
    __syncthreads();

    const int lane = tid & 63;
    const int quad = lane >> 4;
    const int l16 = lane & 15;

    s16x8 Bf[6][KS];
#pragma unroll
    for (int t = 0; t < 6; ++t)
#pragma unroll
        for (int s = 0; s < KS; ++s)
            Bf[t][s] = *(const s16x8*)&Wt[(t * 16 + l16) * KP + s * 32 + quad * 8];

    int gw = blockIdx.x * 4 + (tid >> 6);
    int nw = gridDim.x * 4;
    for (int tile = gw; tile < N_NODES / 16; tile += nw) {
        int n0 = tile * 16;
        int row = n0 + l16;
        s16x8 Af[KS];
        if (!PRENORM) {
            const float* Xr = (const float*)Xv + (size_t)row * K;
#pragma unroll
            for (int s = 0; s < KS; ++s) {
                int k0 = s * 32 + quad * 8;
                float4 u = *(const float4*)(Xr + k0);
                float4 v = *(const float4*)(Xr + k0 + 4);
                s16x8 a;
                a[0] = (short)f2bf(u.x); a[1] = (short)f2bf(u.y);
                a[2] = (short)f2bf(u.z); a[3] = (short)f2bf(u.w);
                a[4] = (short)f2bf(v.x); a[5] = (short)f2bf(v.y);
                a[6] = (short)f2bf(v.z); a[7] = (short)f2bf(v.w);
                Af[s] = a;
            }
        } else {
            const unsigned short* Xr = (const unsigned short*)Xv + (size_t)row * HID;
            int g = batch[row];
            const float* ga = gA + g * HID;
            const float* gb = gB + g * HID;
#pragma unroll
            for (int s = 0; s < KS; ++s) {
                int k0 = s * 32 + quad * 8;
                uint4 raw = *(const uint4*)(Xr + k0);
                float4 a0 = *(const float4*)(ga + k0);
                float4 a1 = *(const float4*)(ga + k0 + 4);
                float4 b0 = *(const float4*)(gb + k0);
                float4 b1 = *(const float4*)(gb + k0 + 4);
                s16x8 a;
                a[0] = (short)f2bf(fmaxf(fmaf(bf_lo(raw.x), a0.x, b0.x), 0.f));
                a[1] = (short)f2bf(fmaxf(fmaf(bf_hi(raw.x), a0.y, b0.y), 0.f));
                a[2] = (short)f2bf(fmaxf(fmaf(bf_lo(raw.y), a0.z, b0.z), 0.f));
                a[3] = (short)f2bf(fmaxf(fmaf(bf_hi(raw.y), a0.w, b0.w), 0.f));
                a[4] = (short)f2bf(fmaxf(fmaf(bf_lo(raw.z), a1.x, b1.x), 0.f));
                a[5] = (short)f2bf(fmaxf(fmaf(bf_hi(raw.z), a1.y, b1.y), 0.f));
                a[6] = (short)f2bf(fmaxf(fmaf(bf_lo(raw.w), a1.z, b1.z), 0.f));
                a[7] = (short)f2bf(fmaxf(fmaf(bf_hi(raw.w), a1.w, b1.w), 0.f));
                Af[s] = a;
            }
        }
        f32x4 acc[6];
#pragma unroll
        for (int t = 0; t < 6; ++t) { acc[t][0] = 0.f; acc[t][1] = 0.f; acc[t][2] = 0.f; acc[t][3] = 0.f; }
#pragma unroll
        for (int s = 0; s < KS; ++s)
#pragma unroll
            for (int t = 0; t < 6; ++t)
                acc[t] = __builtin_amdgcn_mfma_f32_16x16x32_bf16(Af[s], Bf[t][s], acc[t], 0, 0, 0);

        float4 dv = *(const float4*)(dinv + n0 + quad * 4);
#pragma unroll
        for (int t = 0; t < 6; ++t) {
            size_t base = (size_t)(n0 + quad * 4) * HID + t * 16 + l16;
            Hp[base]            = f2bf(acc[t][0] * dv.x);
            Hp[base + HID]      = f2bf(acc[t][1] * dv.y);
            Hp[base + 2 * HID]  = f2bf(acc[t][2] * dv.z);
            Hp[base + 3 * HID]  = f2bf(acc[t][3] * dv.w);
        }
    }
}

// ---------- aggregation: block (12,32), 16B rows, unroll 4 (R8-measured optimum) ----------
__global__ __launch_bounds__(384)
void agg_kernel(const int* __restrict__ rowstart, const unsigned short* __restrict__ e_src,
                const float* __restrict__ dinv, const unsigned short* __restrict__ H,
                const float* __restrict__ bias, unsigned short* __restrict__ OUT) {
    int node = blockIdx.x * 32 + threadIdx.y;
    if (node >= N_NODES) return;
    int x = threadIdx.x;   // 0..11, 8 channels each
    const uint4* H8 = (const uint4*)H;
    size_t ridx = (size_t)node * 12 + x;
    float a[8] = {0, 0, 0, 0, 0, 0, 0, 0};
    acc8(a, H8[ridx]);   // self contribution (H' already scaled by dinv)
    int s0 = rowstart[node], s1 = rowstart[node + 1];
    int i = s0;
    for (; i + 4 <= s1; i += 4) {
        int sA = e_src[i], sB = e_src[i + 1], sC = e_src[i + 2], sD = e_src[i + 3];
        uint4 rA = H8[(size_t)sA * 12 + x];
        uint4 rB = H8[(size_t)sB * 12 + x];
        uint4 rC = H8[(size_t)sC * 12 + x];
        uint4 rD = H8[(size_t)sD * 12 + x];
        acc8(a, rA); acc8(a, rB); acc8(a, rC); acc8(a, rD);
    }
    for (; i < s1; ++i)
        acc8(a, H8[(size_t)e_src[i] * 12 + x]);

    float di = dinv[node];
    float4 b0 = *(const float4*)(bias + x * 8);
    float4 b1 = *(const float4*)(bias + x * 8 + 4);
    uint4 ov;
    ov.x = pack2(fmaf(a[0], di, b0.x), fmaf(a[1], di, b0.y));
    ov.y = pack2(fmaf(a[2], di, b0.z), fmaf(a[3], di, b0.w));
    ov.z = pack2(fmaf(a[4], di, b1.x), fmaf(a[5], di, b1.y));
    ov.w = pack2(fmaf(a[6], di, b1.z), fmaf(a[7], di, b1.w));
    ((uint4*)OUT)[ridx] = ov;
}

// ---------- GraphNorm: partial sums + last-block finalize ----------
__global__ __launch_bounds__(768)
void gn_partial(const unsigned short* __restrict__ Xb, const int* __restrict__ gstart,
                const int* __restrict__ gend, float* __restrict__ gSum, float* __restrict__ gSq,
                int* __restrict__ done, const float* __restrict__ w, const float* __restrict__ b,
                const float* __restrict__ a, float* __restrict__ gA, float* __restrict__ gB) {
    __shared__ float4 sSum[32][24];
    __shared__ float4 sSq[32][24];
    __shared__ int lastFlag;
    int g = blockIdx.x, sl = blockIdx.y;
    int x = threadIdx.x, ty = threadIdx.y;
    int s = gstart[g], e = gend[g];
    float sx = 0, sy = 0, sz = 0, sw = 0, qx = 0, qy = 0, qz = 0, qw = 0;
    if (s <= e) {
        int cnt = e - s + 1;
        int per = (cnt + SLICES - 1) / SLICES;
        int n0 = s + sl * per;
        int n1 = min(n0 + per - 1, e);
        const ushort4* X4 = (const ushort4*)Xb;
        for (int n = n0 + ty; n <= n1; n += 32) {
            ushort4 h = X4[(size_t)n * 24 + x];
            float vx = bf2f(h.x), vy = bf2f(h.y), vz = bf2f(h.z), vw = bf2f(h.w);
            sx += vx; qx = fmaf(vx, vx, qx);
            sy += vy; qy = fmaf(vy, vy, qy);
            sz += vz; qz = fmaf(vz, vz, qz);
            sw += vw; qw = fmaf(vw, vw, qw);
        }
    }
    sSum[ty][x] = make_float4(sx, sy, sz, sw);
    sSq[ty][x] = make_float4(qx, qy, qz, qw);
    __syncthreads();
    for (int off = 16; off > 0; off >>= 1) {
        if (ty < off) {
            float4 A = sSum[ty + off][x], B = sSum[ty][x];
            sSum[ty][x] = make_float4(A.x + B.x, A.y + B.y, A.z + B.z, A.w + B.w);
            float4 C = sSq[ty + off][x], D = sSq[ty][x];
            sSq[ty][x] = make_float4(C.x + D.x, C.y + D.y, C.z + D.z, C.w + D.w);
        }
        __syncthreads();
    }
    if (ty == 0) {
        float4 S = sSum[0][x], Q = sSq[0][x];
        atomicAdd(&gSum[g * HID + x * 4 + 0], S.x);
        atomicAdd(&gSum[g * HID + x * 4 + 1], S.y);
        atomicAdd(&gSum[g * HID + x * 4 + 2], S.z);
        atomicAdd(&gSum[g * HID + x * 4 + 3], S.w);
        atomicAdd(&gSq[g * HID + x * 4 + 0], Q.x);
        atomicAdd(&gSq[g * HID + x * 4 + 1], Q.y);
        atomicAdd(&gSq[g * HID + x * 4 + 2], Q.z);
        atomicAdd(&gSq[g * HID + x * 4 + 3], Q.w);
        __threadfence();
    }
    __syncthreads();
    if (ty == 0 && x == 0) {
        int old = atomicAdd(&done[g], 1);
        lastFlag = (old == SLICES - 1) ? 1 : 0;
    }
    __syncthreads();
    if (lastFlag) {
        int t = ty * 24 + x;
        if (t < HID) {
            float S = atomicAdd(&gSum[g * HID + t], 0.0f);   // coherent read
            float Q = atomicAdd(&gSq[g * HID + t], 0.0f);
            float A = 0.f, B = 0.f;
            if (s <= e) {
                float cnt = (float)(e - s + 1);
                float mean = S / cnt;
                float alpha = a[t];
                float var = Q / cnt - (2.f * alpha - alpha * alpha) * mean * mean;
                var = fmaxf(var, 0.f);
                float rsv = rsqrtf(var + 1e-5f);
                A = w[t] * rsv;
                B = b[t] - alpha * mean * A;
            }
            gA[g * HID + t] = A;
            gB[g * HID + t] = B;
        }
    }
}

// final apply: d_out(f32) = relu(bf16(X)*A[g]+B[g]); block (12,32)
__global__ __launch_bounds__(384)
void gn_apply(const unsigned short* __restrict__ Xb, const int* __restrict__ batch,
              const float* __restrict__ gA, const float* __restrict__ gB,
              float* __restrict__ Y) {
    int n = blockIdx.x * 32 + threadIdx.y;
    if (n >= N_NODES) return;
    int x = threadIdx.x;
    int g = batch[n];
    uint4 h = ((const uint4*)Xb)[(size_t)n * 12 + x];
    const float* ga = gA + g * HID + x * 8;
    const float* gb = gB + g * HID + x * 8;
    float4 a0 = *(const float4*)ga, a1 = *(const float4*)(ga + 4);
    float4 b0 = *(const float4*)gb, b1 = *(const float4*)(gb + 4);
    float4 o0, o1;
    o0.x = fmaxf(fmaf(bf_lo(h.x), a0.x, b0.x), 0.f);
    o0.y = fmaxf(fmaf(bf_hi(h.x), a0.y, b0.y), 0.f);
    o0.z = fmaxf(fmaf(bf_lo(h.y), a0.z, b0.z), 0.f);
    o0.w = fmaxf(fmaf(bf_hi(h.y), a0.w, b0.w), 0.f);
    o1.x = fmaxf(fmaf(bf_lo(h.z), a1.x, b1.x), 0.f);
    o1.y = fmaxf(fmaf(bf_hi(h.z), a1.y, b1.y), 0.f);
    o1.z = fmaxf(fmaf(bf_lo(h.w), a1.z, b1.z), 0.f);
    o1.w = fmaxf(fmaf(bf_hi(h.w), a1.w, b1.w), 0.f);
    float* yr = Y + (size_t)n * HID + x * 8;
    *(float4*)yr = o0;
    *(float4*)(yr + 4) = o1;
}

extern "C" void kernel_launch(void* const* d_in, const int* in_sizes, int n_in,
                              void* d_out, int out_size, void* d_ws, size_t ws_size,
                              hipStream_t stream) {
    const float* x     = (const float*)d_in[0];
    const int*   edge  = (const int*)d_in[1];
    const int*   batch = (const int*)d_in[2];
    const float* W1    = (const float*)d_in[3];
    const float* b1    = (const float*)d_in[4];
    const float* gn1_w = (const float*)d_in[5];
    const float* gn1_b = (const float*)d_in[6];
    const float* gn1_a = (const float*)d_in[7];
    const float* W2    = (const float*)d_in[8];
    const float* b2    = (const float*)d_in[9];
    const float* gn2_w = (const float*)d_in[10];
    const float* gn2_b = (const float*)d_in[11];
    const float* gn2_a = (const float*)d_in[12];
    float* out = (float*)d_out;

    const int* srcv = edge;
    const int* dstv = edge + N_EDGES;

    float* ws   = (float*)d_ws;
    float* dinv = ws;                          // 50048 f
    float* gA   = dinv + 50048;                // 6144 f
    float* gB   = gA + 6144;                   // 6144 f
    // --- single zero-memset block: stats + ALL counters (distinct arrays!) ---
    float* zb    = gB + 6144;
    float* gSum1 = zb;                         // 6144
    float* gSq1  = gSum1 + 6144;               // 6144
    float* gSum2 = gSq1 + 6144;                // 6144
    float* gSq2  = gSum2 + 6144;               // 6144
    int* done1   = (int*)(gSq2 + 6144);        // 64 (per-graph, layer 1)
    int* done2   = done1 + 64;                 // 64 (per-graph, layer 2)
    int* p2done  = done2 + 64;                 // 64 (scalar + pad)
    const size_t ZB_BYTES = (4 * 6144 + 3 * 64) * sizeof(float);
    // --- rest (written deterministically by kernels, no init needed) ---
    int* gstart  = p2done + 64;                // 64
    int* gend    = gstart + 64;                // 64
    int* rowstart   = gend + 64;               // 50008
    int* chunkHist  = rowstart + 50008;        // 39200
    int* offTabRel  = chunkHist + NCHK * NBUCK;// 39200
    int* bucketTot  = offTabRel + NCHK * NBUCK;// 200 (pad)
    int* bucketBase = bucketTot + 200;         // 200 (pad, 197 used)
    unsigned int* epacked = (unsigned int*)(bucketBase + 200);      // 800000 u32
    unsigned short* e_src16 = (unsigned short*)(epacked + N_EDGES); // 800000 u16
    unsigned short* Hbf = e_src16 + N_EDGES;                        // 4.8M bf16
    unsigned short* Obf = Hbf + (size_t)N_NODES * HID;              // 4.8M bf16

    // ---- preprocessing ----
    hipMemsetAsync(zb, 0, ZB_BYTES, stream);
    p1_hist<<<NCHK, 256, 0, stream>>>(dstv, chunkHist, batch, gstart, gend);
    p2_scan<<<NBUCK, 256, 0, stream>>>(chunkHist, offTabRel, bucketTot, bucketBase,
                                       rowstart, p2done);
    p3_place<<<NCHK, 256, 0, stream>>>(srcv, dstv, offTabRel, bucketBase, epacked);
    p4_fine<<<NBUCK, 256, 0, stream>>>(epacked, bucketBase, rowstart, dinv, e_src16);

    const dim3 blk12x32(12, 32);
    const dim3 blk24x32(24, 32);
    const int nodeGrid32 = (N_NODES + 31) / 32;   // 1563

    // ---------- layer 1 ----------
    gemm_mfma<IN_C, false><<<391, 256, 0, stream>>>(x, W1, dinv, nullptr, nullptr, nullptr, Hbf);
    agg_kernel<<<nodeGrid32, blk12x32, 0, stream>>>(rowstart, e_src16, dinv, Hbf, b1, Obf);
    gn_partial<<<dim3(N_GRAPHS, SLICES), blk24x32, 0, stream>>>(Obf, gstart, gend, gSum1, gSq1,
                                                                done1, gn1_w, gn1_b, gn1_a, gA, gB);

    // ---------- layer 2 (gn_apply+relu of layer 1 fused into A-frag load) ----------
    gemm_mfma<HID, true><<<391, 256, 0, stream>>>(Obf, W2, dinv, batch, gA, gB, Hbf);
    agg_kernel<<<nodeGrid32, blk12x32, 0, stream>>>(rowstart, e_src16, dinv, Hbf, b2, Obf);
    gn_partial<<<dim3(N_GRAPHS, SLICES), blk24x32, 0, stream>>>(Obf, gstart, gend, gSum2, gSq2,
                                                                done2, gn2_w, gn2_b, gn2_a, gA, gB);
    gn_apply<<<nodeGrid32, blk12x32, 0, stream>>>(Obf, batch, gA, gB, out);
}